// Round 1
// baseline (284.935 us; speedup 1.0000x reference)
//
#include <hip/hip_runtime.h>

#define B_DIM 1024
#define S_DIM 16
#define H_DIM 1024
#define N_DIM 16384
#define L_DIM 128
#define KX    (H_DIM + L_DIM)   // 1152, divisible by 64

typedef __bf16 bf16_8 __attribute__((ext_vector_type(8)));
typedef float  f32x4  __attribute__((ext_vector_type(4)));

// round-to-nearest-even f32 -> bf16 (bit trick; inputs finite)
__device__ __forceinline__ unsigned short f2bf(float f) {
    unsigned int u = __float_as_uint(f);
    u += 0x7fffu + ((u >> 16) & 1u);
    return (unsigned short)(u >> 16);
}

// ---------------------------------------------------------------------------
// Kernel 1: per-row label aggregation + build bf16 GEMM input row [cls | agg]
// 1 block per batch row. Wave-private LDS bins to cut atomic contention 4x.
// ---------------------------------------------------------------------------
__global__ __launch_bounds__(256) void k_agg(
    const float* __restrict__ feats,   // (B, S, H)
    const float* __restrict__ sims,    // (B, N)
    const int*   __restrict__ labels,  // (B, N)
    unsigned short* __restrict__ xin)  // (B, KX) bf16
{
    __shared__ float bins[4][L_DIM];
    const int b = blockIdx.x;
    const int t = threadIdx.x;
    const int w = t >> 6;

    for (int i = t; i < 4 * L_DIM; i += 256) ((float*)bins)[i] = 0.f;
    __syncthreads();

    const float4* s4 = (const float4*)(sims   + (size_t)b * N_DIM);
    const int4*   l4 = (const int4*)  (labels + (size_t)b * N_DIM);
    #pragma unroll 4
    for (int v = t; v < N_DIM / 4; v += 256) {
        float4 s = s4[v];
        int4   li = l4[v];
        atomicAdd(&bins[w][li.x], s.x);
        atomicAdd(&bins[w][li.y], s.y);
        atomicAdd(&bins[w][li.z], s.z);
        atomicAdd(&bins[w][li.w], s.w);
    }
    __syncthreads();

    unsigned short* xrow = xin + (size_t)b * KX;
    // cls = features[b, 0, :]: 1024 floats, one float4 per thread
    const float4* c4 = (const float4*)(feats + (size_t)b * (S_DIM * H_DIM));
    float4 c = c4[t];
    ushort4 p;
    p.x = f2bf(c.x); p.y = f2bf(c.y); p.z = f2bf(c.z); p.w = f2bf(c.w);
    *(ushort4*)(xrow + t * 4) = p;

    if (t < L_DIM) {
        float s = bins[0][t] + bins[1][t] + bins[2][t] + bins[3][t];
        xrow[H_DIM + t] = f2bf(s * (1.0f / N_DIM));
    }
}

// ---------------------------------------------------------------------------
// Kernel 2: f32 -> bf16 conversion of both weight matrices (grid-stride)
// ---------------------------------------------------------------------------
__global__ __launch_bounds__(256) void k_cvt(
    const float* __restrict__ w1, const float* __restrict__ w2,
    unsigned short* __restrict__ o1, unsigned short* __restrict__ o2,
    int n1v, int n2v)  // counts in float4 units
{
    int idx = blockIdx.x * 256 + threadIdx.x;
    int stride = gridDim.x * 256;
    for (int i = idx; i < n1v + n2v; i += stride) {
        const float4* src; unsigned short* dst; int j;
        if (i < n1v) { src = (const float4*)w1; dst = o1; j = i; }
        else         { src = (const float4*)w2; dst = o2; j = i - n1v; }
        float4 v = src[j];
        ushort4 p;
        p.x = f2bf(v.x); p.y = f2bf(v.y); p.z = f2bf(v.z); p.w = f2bf(v.w);
        *(ushort4*)(dst + j * 4) = p;
    }
}

// ---------------------------------------------------------------------------
// bf16 MFMA GEMM, C = A(MxK) . B(NxK)^T, both row-major with K contiguous.
// 64x64 tile, BK=64, 256 threads = 4 waves, each wave owns a 32x32 quadrant
// (2x2 fragments of 16x16x32). LDS rows padded +8 bf16 -> 144 B stride (2-way
// bank aliasing only, free). EPI=0: bias+tanh -> bf16; EPI=1: bias -> f32.
// ---------------------------------------------------------------------------
template <int EPI>
__global__ __launch_bounds__(256) void k_gemm_bt(
    const unsigned short* __restrict__ A,   // M x K bf16
    const unsigned short* __restrict__ Bm,  // N x K bf16
    const float* __restrict__ bias,         // N
    void* __restrict__ Cout,
    int M, int N, int K, int ldc)
{
    __shared__ __align__(16) unsigned short As[64][72];
    __shared__ __align__(16) unsigned short Bs[64][72];

    const int t    = threadIdx.x;
    const int lane = t & 63;
    const int w    = t >> 6;
    const int wm   = w >> 1, wn = w & 1;
    const int m0   = blockIdx.y * 64;
    const int n0   = blockIdx.x * 64;
    const int lr   = lane & 15;
    const int lk   = (lane >> 4) * 8;

    f32x4 acc[2][2] = {};

    for (int k0 = 0; k0 < K; k0 += 64) {
        // stage: 64 rows x 128 B per operand; each thread 2x 16B per operand
        #pragma unroll
        for (int i = 0; i < 2; ++i) {
            int li  = t + i * 256;      // 0..511
            int row = li >> 3;          // 8 chunks of 16B per row
            int c8  = (li & 7) * 8;     // bf16 offset within row
            *(uint4*)(&As[row][c8]) =
                *(const uint4*)(A + (size_t)(m0 + row) * K + k0 + c8);
            *(uint4*)(&Bs[row][c8]) =
                *(const uint4*)(Bm + (size_t)(n0 + row) * K + k0 + c8);
        }
        __syncthreads();

        #pragma unroll
        for (int ks = 0; ks < 2; ++ks) {
            int kk = ks * 32 + lk;
            bf16_8 a0 = *(const bf16_8*)(&As[wm * 32 +      lr][kk]);
            bf16_8 a1 = *(const bf16_8*)(&As[wm * 32 + 16 + lr][kk]);
            bf16_8 b0 = *(const bf16_8*)(&Bs[wn * 32 +      lr][kk]);
            bf16_8 b1 = *(const bf16_8*)(&Bs[wn * 32 + 16 + lr][kk]);
            acc[0][0] = __builtin_amdgcn_mfma_f32_16x16x32_bf16(a0, b0, acc[0][0], 0, 0, 0);
            acc[0][1] = __builtin_amdgcn_mfma_f32_16x16x32_bf16(a0, b1, acc[0][1], 0, 0, 0);
            acc[1][0] = __builtin_amdgcn_mfma_f32_16x16x32_bf16(a1, b0, acc[1][0], 0, 0, 0);
            acc[1][1] = __builtin_amdgcn_mfma_f32_16x16x32_bf16(a1, b1, acc[1][1], 0, 0, 0);
        }
        __syncthreads();
    }

    // epilogue: C/D layout col = lane&15, row = (lane>>4)*4 + reg  [m89]
    const int rbase = m0 + wm * 32 + (lane >> 4) * 4;
    const int cbase = n0 + wn * 32 + lr;
    #pragma unroll
    for (int i = 0; i < 2; ++i) {
        #pragma unroll
        for (int j = 0; j < 2; ++j) {
            int col = cbase + j * 16;
            float bv = bias[col];
            #pragma unroll
            for (int r = 0; r < 4; ++r) {
                int row = rbase + i * 16 + r;
                float v = acc[i][j][r] + bv;
                if (EPI == 0) {
                    v = tanhf(v);
                    ((unsigned short*)Cout)[(size_t)row * ldc + col] = f2bf(v);
                } else {
                    ((float*)Cout)[(size_t)row * ldc + col] = v;
                }
            }
        }
    }
}

// ---------------------------------------------------------------------------
extern "C" void kernel_launch(void* const* d_in, const int* in_sizes, int n_in,
                              void* d_out, int out_size, void* d_ws, size_t ws_size,
                              hipStream_t stream) {
    const float* feats   = (const float*)d_in[0];
    const float* sims    = (const float*)d_in[1];
    const int*   labels  = (const int*)  d_in[2];
    const float* dense_w = (const float*)d_in[3];
    const float* dense_b = (const float*)d_in[4];
    const float* out_w   = (const float*)d_in[5];
    const float* out_b   = (const float*)d_in[6];
    float* out = (float*)d_out;

    // workspace layout (bf16 buffers), total ~7.1 MB
    unsigned short* xin  = (unsigned short*)d_ws;               // B x KX
    unsigned short* wd   = xin  + (size_t)B_DIM * KX;           // H x KX
    unsigned short* wo   = wd   + (size_t)H_DIM * KX;           // L x H
    unsigned short* xmid = wo   + (size_t)L_DIM * H_DIM;        // B x H

    k_agg<<<B_DIM, 256, 0, stream>>>(feats, sims, labels, xin);

    int n1v = (H_DIM * KX) / 4;
    int n2v = (L_DIM * H_DIM) / 4;
    k_cvt<<<512, 256, 0, stream>>>(dense_w, out_w, wd, wo, n1v, n2v);

    dim3 g1(H_DIM / 64, B_DIM / 64);   // (16, 16)
    k_gemm_bt<0><<<g1, 256, 0, stream>>>(xin, wd, dense_b, (void*)xmid,
                                         B_DIM, H_DIM, KX, H_DIM);

    dim3 g2(L_DIM / 64, B_DIM / 64);   // (2, 16)
    k_gemm_bt<1><<<g2, 256, 0, stream>>>(xmid, wo, out_b, (void*)out,
                                         B_DIM, L_DIM, H_DIM, L_DIM);
}

// Round 2
// 247.725 us; speedup vs baseline: 1.1502x; 1.1502x over previous
//
#include <hip/hip_runtime.h>

#define B_DIM 1024
#define S_DIM 16
#define H_DIM 1024
#define N_DIM 16384
#define L_DIM 128
#define KX    (H_DIM + L_DIM)   // 1152, divisible by 64

typedef __bf16 bf16_8 __attribute__((ext_vector_type(8)));
typedef float  f32x4  __attribute__((ext_vector_type(4)));

// round-to-nearest-even f32 -> bf16 (bit trick; inputs finite)
__device__ __forceinline__ unsigned short f2bf(float f) {
    unsigned int u = __float_as_uint(f);
    u += 0x7fffu + ((u >> 16) & 1u);
    return (unsigned short)(u >> 16);
}

// async global -> LDS, 16 B per lane (dest must be uniform-base + lane*16)
#define GLD16(gp, lp)                                                          \
    __builtin_amdgcn_global_load_lds(                                          \
        (const __attribute__((address_space(1))) void*)(gp),                   \
        (__attribute__((address_space(3))) void*)(lp), 16, 0, 0)

// ---------------------------------------------------------------------------
// Kernel 1: per-row label aggregation + build bf16 GEMM input row [cls | agg]
// 64 bin copies (1 per 4 threads), stride 129 -> atomic bank = (c+label)%32:
// near-conflict-free LDS atomics (was 4 copies -> ~200 cyc/atomic-waveop).
// ---------------------------------------------------------------------------
__global__ __launch_bounds__(256) void k_agg(
    const float* __restrict__ feats,   // (B, S, H)
    const float* __restrict__ sims,    // (B, N)
    const int*   __restrict__ labels,  // (B, N)
    unsigned short* __restrict__ xin)  // (B, KX) bf16
{
    __shared__ float bins[64][L_DIM + 1];   // 33 KB -> 4 blocks/CU
    const int b = blockIdx.x;
    const int t = threadIdx.x;
    const int c = t >> 2;                   // copy per 4-thread group

    float* flat = (float*)bins;
    for (int i = t; i < 64 * (L_DIM + 1); i += 256) flat[i] = 0.f;
    __syncthreads();

    const float4* s4 = (const float4*)(sims   + (size_t)b * N_DIM);
    const int4*   l4 = (const int4*)  (labels + (size_t)b * N_DIM);
    #pragma unroll 4
    for (int v = t; v < N_DIM / 4; v += 256) {
        float4 s  = s4[v];
        int4   li = l4[v];
        atomicAdd(&bins[c][li.x], s.x);
        atomicAdd(&bins[c][li.y], s.y);
        atomicAdd(&bins[c][li.z], s.z);
        atomicAdd(&bins[c][li.w], s.w);
    }
    __syncthreads();

    unsigned short* xrow = xin + (size_t)b * KX;
    // cls = features[b, 0, :]: 1024 floats, one float4 per thread
    const float4* c4 = (const float4*)(feats + (size_t)b * (S_DIM * H_DIM));
    float4 cv = c4[t];
    ushort4 p;
    p.x = f2bf(cv.x); p.y = f2bf(cv.y); p.z = f2bf(cv.z); p.w = f2bf(cv.w);
    *(ushort4*)(xrow + t * 4) = p;

    if (t < L_DIM) {
        float s = 0.f;
        #pragma unroll
        for (int cc = 0; cc < 64; ++cc) s += bins[cc][t];  // bank (cc+t)%32: free
        xrow[H_DIM + t] = f2bf(s * (1.0f / N_DIM));
    }
}

// ---------------------------------------------------------------------------
// Kernel 2: f32 -> bf16 conversion of both weight matrices (grid-stride)
// ---------------------------------------------------------------------------
__global__ __launch_bounds__(256) void k_cvt(
    const float* __restrict__ w1, const float* __restrict__ w2,
    unsigned short* __restrict__ o1, unsigned short* __restrict__ o2,
    int n1v, int n2v)  // counts in float4 units
{
    int idx = blockIdx.x * 256 + threadIdx.x;
    int stride = gridDim.x * 256;
    for (int i = idx; i < n1v + n2v; i += stride) {
        const float4* src; unsigned short* dst; int j;
        if (i < n1v) { src = (const float4*)w1; dst = o1; j = i; }
        else         { src = (const float4*)w2; dst = o2; j = i - n1v; }
        float4 v = src[j];
        ushort4 p;
        p.x = f2bf(v.x); p.y = f2bf(v.y); p.z = f2bf(v.z); p.w = f2bf(v.w);
        *(ushort4*)(dst + j * 4) = p;
    }
}

// ---------------------------------------------------------------------------
// bf16 MFMA GEMM, C = A(MxK) . B(NxK)^T, both row-major, K contiguous.
// 64x64 tile, BK=64, 4 waves (each a 32x32 quadrant, 2x2 frags of 16x16x32).
// Staging: global_load_lds 16B, XOR-swizzled SOURCE (granule ^= row&7) with
// linear LDS dest + swizzled ds_read (G21 both-sides) -> ~2-way conflicts.
// Pipeline: 3 LDS buffers, 2-deep prefetch, counted vmcnt (never 0 mid-loop),
// raw s_barrier (avoids the compiler's vmcnt(0) drain at __syncthreads).
// EPI=0: bias+tanh -> bf16; EPI=1: bias -> f32.
// ---------------------------------------------------------------------------
template <int EPI>
__global__ __launch_bounds__(256) void k_gemm_bt(
    const unsigned short* __restrict__ A,   // M x K bf16
    const unsigned short* __restrict__ Bm,  // N x K bf16
    const float* __restrict__ bias,         // N
    void* __restrict__ Cout,
    int M, int N, int K, int ldc)
{
    __shared__ __align__(16) unsigned short sm[3][2][64 * 64];  // 48 KB

    const int t    = threadIdx.x;
    const int lane = t & 63;
    const int w    = t >> 6;
    const int wm   = w >> 1, wn = w & 1;
    const int m0   = blockIdx.y * 64;
    const int n0   = blockIdx.x * 64;
    const int lr   = lane & 15;
    const int hi   = lane >> 4;

    // per-thread staging offsets: 2 chunks of 16B per operand per tile
    int srcj[2];
    #pragma unroll
    for (int j = 0; j < 2; ++j) {
        int li  = t + j * 256;      // granule index 0..511
        int row = li >> 3;
        int g   = li & 7;
        int gs  = g ^ (row & 7);    // pre-swizzled source granule
        srcj[j] = row * K + gs * 8; // elements
    }
    const size_t aBase = (size_t)m0 * K;
    const size_t bBase = (size_t)n0 * K;

    const int nt = K >> 6;
    f32x4 acc[2][2] = {};

#define STAGE(buf, k0_)                                                        \
    do {                                                                       \
        _Pragma("unroll")                                                      \
        for (int j = 0; j < 2; ++j) {                                          \
            int li = t + j * 256;                                              \
            GLD16(A  + aBase + (size_t)(srcj[j] + (k0_)), &sm[buf][0][li * 8]);\
            GLD16(Bm + bBase + (size_t)(srcj[j] + (k0_)), &sm[buf][1][li * 8]);\
        }                                                                      \
    } while (0)

    STAGE(0, 0);
    if (nt > 1) STAGE(1, 64);

    int cur = 0;
    for (int ti = 0; ti < nt; ++ti) {
        int b2 = cur + 2; if (b2 >= 3) b2 -= 3;
        if (ti + 2 < nt) {
            STAGE(b2, (ti + 2) << 6);
            asm volatile("s_waitcnt vmcnt(8)" ::: "memory");
        } else if (ti + 1 < nt) {
            asm volatile("s_waitcnt vmcnt(4)" ::: "memory");
        } else {
            asm volatile("s_waitcnt vmcnt(0)" ::: "memory");
        }
        __builtin_amdgcn_s_barrier();
        asm volatile("" ::: "memory");

        const unsigned short* As = sm[cur][0];
        const unsigned short* Bs = sm[cur][1];
        #pragma unroll
        for (int ks = 0; ks < 2; ++ks) {
            const int gl = ks * 4 + hi;               // logical granule of kk
            const int ga = (gl ^ (lr & 7)) * 8;       // swizzled elem offset
            bf16_8 a0 = *(const bf16_8*)(As + (wm * 32 +      lr) * 64 + ga);
            bf16_8 a1 = *(const bf16_8*)(As + (wm * 32 + 16 + lr) * 64 + ga);
            bf16_8 b0 = *(const bf16_8*)(Bs + (wn * 32 +      lr) * 64 + ga);
            bf16_8 b1 = *(const bf16_8*)(Bs + (wn * 32 + 16 + lr) * 64 + ga);
            acc[0][0] = __builtin_amdgcn_mfma_f32_16x16x32_bf16(a0, b0, acc[0][0], 0, 0, 0);
            acc[0][1] = __builtin_amdgcn_mfma_f32_16x16x32_bf16(a0, b1, acc[0][1], 0, 0, 0);
            acc[1][0] = __builtin_amdgcn_mfma_f32_16x16x32_bf16(a1, b0, acc[1][0], 0, 0, 0);
            acc[1][1] = __builtin_amdgcn_mfma_f32_16x16x32_bf16(a1, b1, acc[1][1], 0, 0, 0);
        }

        asm volatile("" ::: "memory");
        __builtin_amdgcn_s_barrier();
        cur = cur + 1; if (cur >= 3) cur = 0;
    }

    // epilogue: C/D layout col = lane&15, row = (lane>>4)*4 + reg  [m89]
    const int rbase = m0 + wm * 32 + hi * 4;
    const int cbase = n0 + wn * 32 + lr;
    #pragma unroll
    for (int i = 0; i < 2; ++i) {
        #pragma unroll
        for (int j = 0; j < 2; ++j) {
            int col = cbase + j * 16;
            float bv = bias[col];
            #pragma unroll
            for (int r = 0; r < 4; ++r) {
                int row = rbase + i * 16 + r;
                float v = acc[i][j][r] + bv;
                if (EPI == 0) {
                    v = tanhf(v);
                    ((unsigned short*)Cout)[(size_t)row * ldc + col] = f2bf(v);
                } else {
                    ((float*)Cout)[(size_t)row * ldc + col] = v;
                }
            }
        }
    }
#undef STAGE
}

// ---------------------------------------------------------------------------
extern "C" void kernel_launch(void* const* d_in, const int* in_sizes, int n_in,
                              void* d_out, int out_size, void* d_ws, size_t ws_size,
                              hipStream_t stream) {
    const float* feats   = (const float*)d_in[0];
    const float* sims    = (const float*)d_in[1];
    const int*   labels  = (const int*)  d_in[2];
    const float* dense_w = (const float*)d_in[3];
    const float* dense_b = (const float*)d_in[4];
    const float* out_w   = (const float*)d_in[5];
    const float* out_b   = (const float*)d_in[6];
    float* out = (float*)d_out;

    // workspace layout (bf16 buffers), total ~7.1 MB
    unsigned short* xin  = (unsigned short*)d_ws;               // B x KX
    unsigned short* wd   = xin  + (size_t)B_DIM * KX;           // H x KX
    unsigned short* wo   = wd   + (size_t)H_DIM * KX;           // L x H
    unsigned short* xmid = wo   + (size_t)L_DIM * H_DIM;        // B x H

    k_agg<<<B_DIM, 256, 0, stream>>>(feats, sims, labels, xin);

    int n1v = (H_DIM * KX) / 4;
    int n2v = (L_DIM * H_DIM) / 4;
    k_cvt<<<512, 256, 0, stream>>>(dense_w, out_w, wd, wo, n1v, n2v);

    dim3 g1(H_DIM / 64, B_DIM / 64);   // (16, 16)
    k_gemm_bt<0><<<g1, 256, 0, stream>>>(xin, wd, dense_b, (void*)xmid,
                                         B_DIM, H_DIM, KX, H_DIM);

    dim3 g2(L_DIM / 64, B_DIM / 64);   // (2, 16)
    k_gemm_bt<1><<<g2, 256, 0, stream>>>(xmid, wo, out_b, (void*)out,
                                         B_DIM, L_DIM, H_DIM, L_DIM);
}